// Round 5
// baseline (150.172 us; speedup 1.0000x reference)
//
#include <hip/hip_runtime.h>
#include <hip/hip_bf16.h>

// REN forward: BATCH=32768, N_X=64, N_UNITS=256, N_Y=32, N_U=64
typedef __attribute__((ext_vector_type(8))) short short8;
typedef __attribute__((ext_vector_type(4))) float floatx4;
typedef __attribute__((ext_vector_type(2))) float floatx2;

#define MFMA16 __builtin_amdgcn_mfma_f32_16x16x32_bf16

__device__ inline unsigned short bf16_rn(float f) {
    return (unsigned short)((__float_as_uint(f) + 0x8000u) >> 16);
}
// Packed f32->bf16 (RNE), value-based: no address-taken private arrays.
__device__ __attribute__((always_inline)) inline short8 pack8v(float4 a, float4 b) {
    union { short8 s; unsigned int u[4]; } r;
    union { __hip_bfloat162 h; unsigned int u; } c;
    c.h = __float22bfloat162_rn(make_float2(a.x, a.y)); r.u[0] = c.u;
    c.h = __float22bfloat162_rn(make_float2(a.z, a.w)); r.u[1] = c.u;
    c.h = __float22bfloat162_rn(make_float2(b.x, b.y)); r.u[2] = c.u;
    c.h = __float22bfloat162_rn(make_float2(b.z, b.w)); r.u[3] = c.u;
    return r.s;
}

// Issue-early loads: volatile asm global_load_dwordx4. Fixed program position
// (volatile asms keep mutual order), no compiler-inserted wait at use sites,
// 13 distinct destination tuples forced live -> all loads in flight at once.
__device__ __attribute__((always_inline)) inline short8 gload16(const unsigned short* p) {
    short8 d;
    asm volatile("global_load_dwordx4 %0, %1, off" : "=v"(d) : "v"(p));
    return d;
}
__device__ __attribute__((always_inline)) inline floatx4 gload16f(const float* p) {
    floatx4 d;
    asm volatile("global_load_dwordx4 %0, %1, off" : "=v"(d) : "v"(p));
    return d;
}

// ---------------------------------------------------------------------------
// Prep13: (unchanged)
// ---------------------------------------------------------------------------
__global__ __launch_bounds__(64) void ren_prep13(
    const float* __restrict__ B2, const float* __restrict__ C2,
    const float* __restrict__ D12, const float* __restrict__ D21,
    const float* __restrict__ St, const float* __restrict__ Q,
    const float* __restrict__ Rinv,
    float* __restrict__ lT1, float* __restrict__ t1,
    float* __restrict__ lT2, float* __restrict__ t2,
    unsigned short* __restrict__ Wvb, unsigned short* __restrict__ C2b,
    unsigned short* __restrict__ D21b)
{
    const int t = threadIdx.x;
    const int blk = blockIdx.x;
    if (blk >= 384) {   // bf16-copy role (uniform branch)
        const int id = (blk - 384) * 64 + t;
        if (id < 16384) {
            Wvb[(id >> 6) * 128 + 64 + (id & 63)] = bf16_rn(D12[id]);
        } else if (id < 16384 + 2048) {
            C2b[id - 16384] = bf16_rn(C2[id - 16384]);
        } else if (id < 16384 + 2048 + 8192) {
            D21b[id - 18432] = bf16_rn(D21[id - 18432]);
        }
        return;
    }

    __shared__ float stl[64 * 33];  // St (64x32), padded
    __shared__ float colbuf[32];    // this block's C2/D21 column
    __shared__ float s1[64];

    const int r = blk;   // 0..383
    const int c = t;     // 0..63
#pragma unroll
    for (int j = 0; j < 32; j++) {
        const int id = j * 64 + t;
        stl[(id >> 5) * 33 + (id & 31)] = St[id];
    }
    if (t < 32)
        colbuf[t] = (r < 64) ? C2[t * 64 + r]
                  : (r < 320 ? D21[t * 256 + (r - 64)] : 0.f);
    __syncthreads();

    float v1;
    if (r < 64) {
        float s = 0.f;
#pragma unroll
        for (int p = 0; p < 32; p++) s += stl[c * 33 + p] * colbuf[p];
        v1 = s;
    } else if (r < 320) {
        float s = 0.f;
#pragma unroll
        for (int p = 0; p < 32; p++) s += stl[c * 33 + p] * colbuf[p];
        v1 = s - D12[(r - 64) * 64 + c];
    } else {
        v1 = B2[(r - 320) * 64 + c];
    }
    s1[c] = v1;
    lT1[r * 64 + c] = v1;
    if (c < 32) {
        const float v2 = (r < 320) ? colbuf[c] : 0.f;
        lT2[r * 32 + c] = v2;
    }
    __syncthreads();

    float a = 0.f;
#pragma unroll
    for (int k = 0; k < 64; k++) a += s1[k] * Rinv[k * 64 + c];
    t1[r * 64 + c] = a;

    if (c < 32) {
        float bq = 0.f;
#pragma unroll
        for (int k = 0; k < 32; k++) bq += colbuf[k] * Q[k * 32 + c];
        t2[r * 32 + c] = bq;
    }
}

// ---------------------------------------------------------------------------
// Prep 2: (unchanged)
// ---------------------------------------------------------------------------
__global__ __launch_bounds__(320) void ren_prep2(
    const float* __restrict__ X,
    const float* __restrict__ lT1, const float* __restrict__ t1,
    const float* __restrict__ lT2, const float* __restrict__ t2,
    unsigned short* __restrict__ Wvb, unsigned short* __restrict__ Drowsb,
    float* __restrict__ Dpair, float* __restrict__ lamg)
{
    __shared__ float xcol[384];
    const int c = threadIdx.x;     // 0..319
    const int i = blockIdx.x;      // 0..255 -> H row 64+i
    for (int t = c; t < 384; t += 320) xcol[t] = X[t * 384 + 64 + i];
    __syncthreads();

    float f0 = 0.f, f1 = 0.f, f2 = 0.f, f3 = 0.f;
    float ac[8], au[8], bc8[8], bu[8];
#pragma unroll
    for (int kk = 0; kk < 8; kk++) { ac[kk] = X[kk * 384 + c]; au[kk] = xcol[kk]; }
    for (int k0 = 0; k0 < 384; k0 += 16) {
#pragma unroll
        for (int kk = 0; kk < 8; kk++) {
            bc8[kk] = X[(k0 + 8 + kk) * 384 + c]; bu[kk] = xcol[k0 + 8 + kk];
        }
        f0 += au[0] * ac[0]; f1 += au[1] * ac[1];
        f2 += au[2] * ac[2]; f3 += au[3] * ac[3];
        f0 += au[4] * ac[4]; f1 += au[5] * ac[5];
        f2 += au[6] * ac[6]; f3 += au[7] * ac[7];
        if (k0 + 16 < 384) {
#pragma unroll
            for (int kk = 0; kk < 8; kk++) {
                ac[kk] = X[(k0 + 16 + kk) * 384 + c]; au[kk] = xcol[k0 + 16 + kk];
            }
        }
        f0 += bu[0] * bc8[0]; f1 += bu[1] * bc8[1];
        f2 += bu[2] * bc8[2]; f3 += bu[3] * bc8[3];
        f0 += bu[4] * bc8[4]; f1 += bu[5] * bc8[5];
        f2 += bu[6] * bc8[6]; f3 += bu[7] * bc8[7];
    }

    const float* __restrict__ t1r = t1 + (64 + i) * 64;
    const float* __restrict__ l1r = lT1 + c * 64;
#pragma unroll
    for (int m4 = 0; m4 < 16; m4++) {
        const float4 lv = *(const float4*)(l1r + m4 * 4);
        f0 += t1r[m4 * 4 + 0] * lv.x; f1 += t1r[m4 * 4 + 1] * lv.y;
        f2 += t1r[m4 * 4 + 2] * lv.z; f3 += t1r[m4 * 4 + 3] * lv.w;
    }
    const float* __restrict__ t2r = t2 + (64 + i) * 32;
    const float* __restrict__ l2r = lT2 + c * 32;
#pragma unroll
    for (int m4 = 0; m4 < 8; m4++) {
        const float4 lv = *(const float4*)(l2r + m4 * 4);
        f0 -= t2r[m4 * 4 + 0] * lv.x; f1 -= t2r[m4 * 4 + 1] * lv.y;
        f2 -= t2r[m4 * 4 + 2] * lv.z; f3 -= t2r[m4 * 4 + 3] * lv.w;
    }
    float acc = (f0 + f1) + (f2 + f3) + (((64 + i) == c) ? 0.001f : 0.f);

    if (c < 64) {
        Wvb[i * 128 + c] = bf16_rn(-acc);       // C_1 = -H_21
    } else {
        const int cb = c - 64;
        if (cb == i) lamg[i] = 5.7707801635558536f / acc;  // (2*log2e)*2/H22ii
        if (i < 255) {
            const float dv = (cb <= i - 1) ? -acc : 0.f;
            Drowsb[(i + 1) * 256 + cb] = bf16_rn(dv);
            const int row = i + 1;
            if ((row >> 4) == (cb >> 4)) {      // diagonal 16-block, pair layout
                const int q = row & 15, p = cb & 15;
                Dpair[(row >> 4) * 256 + (q >> 1) * 32 + p * 2 + (q & 1)] = dv;
            }
        } else {
            Drowsb[cb] = 0;
        }
    }
}

// ---------------------------------------------------------------------------
// Triangle: 16-unit blocked tanh recursion, pairwise, two parallel FMA chains.
// Constant-index private arrays only (SROA-safe).
// ---------------------------------------------------------------------------
__device__ __attribute__((always_inline)) inline void triangle16(
    float (&vl)[16], float (&wl)[16],
    const float* __restrict__ dblk, const float* __restrict__ lam)
{
#pragma unroll
    for (int tq = 0; tq < 8; tq++) {
        floatx2 a2, b2;
        a2[0] = vl[2 * tq]; a2[1] = vl[2 * tq + 1];
        b2[0] = 0.f; b2[1] = 0.f;
#pragma unroll
        for (int p4 = 0; p4 < tq; p4++) {
            const float4 d4 = *(const float4*)&dblk[tq * 32 + p4 * 4];  // LDS
            floatx2 de; de[0] = d4.x; de[1] = d4.y;
            floatx2 dz; dz[0] = d4.z; dz[1] = d4.w;
            a2 += de * wl[2 * p4];        // chain A
            b2 += dz * wl[2 * p4 + 1];    // chain B (independent)
        }
        a2 += b2;                          // combine (exact 0 for tq==0)
        floatx2 lm2; lm2[0] = lam[2 * tq]; lm2[1] = lam[2 * tq + 1];  // LDS
        a2 *= lm2;
        const float e0 = __builtin_amdgcn_exp2f(a2[0]);
        const float e1 = __builtin_amdgcn_exp2f(a2[1]);
        wl[2 * tq]     = 1.f - 2.f * __builtin_amdgcn_rcpf(e0 + 1.f);
        wl[2 * tq + 1] = 1.f - 2.f * __builtin_amdgcn_rcpf(e1 + 1.f);
    }
}

// ---------------------------------------------------------------------------
// Main — R12: manual issue-early/wait-late pipeline. R11 proved compiler
// fences can't pin invariant loads (const __restrict -> noclobber; scheduler
// sank them to uses; VGPR stayed 80 = serialized L2 round-trips on the MFMA
// critical path). Now: 13 volatile-asm global_load_dwordx4 at loop top
// (distinct dests forced live), ONE s_waitcnt vmcnt(0) after the triangle,
// tying all 13 values as "+v" in/outs so every MFMA consumer is
// data-dependent on the drain (cannot hoist above it — rule-#18-safe
// without sched_barrier).
// ---------------------------------------------------------------------------
__global__ __launch_bounds__(64, 2) void ren_main(
    const float* __restrict__ u, const float* __restrict__ x0,
    const float* __restrict__ b,
    const unsigned short* __restrict__ Wvb,
    const unsigned short* __restrict__ Drowsb,
    const float* __restrict__ Dpair,
    const float* __restrict__ lamg,
    const unsigned short* __restrict__ C2b,
    const unsigned short* __restrict__ D21b,
    float* __restrict__ out)
{
    __shared__ float buf[16][20];   // acc transpose (stride 20 -> 2-way max)
    __shared__ float dblk[256];     // pair-interleaved 16x16 D tile
    __shared__ float lamsh[256];
    __shared__ float bsh[256];
    __shared__ short8 wsh[8 * 64];  // w A-frags, one 16B frag per lane per chunk

    const int L = threadIdx.x;
    const int col = L & 15;
    const int quad = L >> 4;
    const int row0 = blockIdx.x * 16;

#pragma unroll
    for (int j = 0; j < 4; j++) {
        lamsh[j * 64 + L] = lamg[j * 64 + L];
        bsh[j * 64 + L]   = b[64 + j * 64 + L];
    }
    const short8 zero8 = {0, 0, 0, 0, 0, 0, 0, 0};
#pragma unroll
    for (int c = 0; c < 8; c++) wsh[c * 64 + L] = zero8;   // bf16 +0.0

    // z A-frags: 4 K-chunks of 32 over [x0 | u], batch row m=col
    short8 zf[4];
#pragma unroll
    for (int c = 0; c < 4; c++) {
        const float* p = (c < 2 ? x0 : u) + (long)(row0 + col) * 64 + (c & 1) * 32 + quad * 8;
        const float4 pa = *(const float4*)p;
        const float4 pb = *(const float4*)(p + 4);
        zf[c] = pack8v(pa, pb);
    }

    // ---- prologue: acc for block 0 (v-GEMM only), D tile 0 ----
    floatx4 dcur = *(const floatx4*)(Dpair + 4 * L);
    floatx4 acc0 = {0.f, 0.f, 0.f, 0.f}, acc1 = {0.f, 0.f, 0.f, 0.f};
    {
        short8 v0 = *(const short8*)(Wvb + col * 128 + quad * 8);
        short8 v1 = *(const short8*)(Wvb + col * 128 + 32 + quad * 8);
        short8 v2 = *(const short8*)(Wvb + col * 128 + 64 + quad * 8);
        short8 v3 = *(const short8*)(Wvb + col * 128 + 96 + quad * 8);
        acc0 = MFMA16(zf[0], v0, acc0, 0, 0, 0);
        acc1 = MFMA16(zf[1], v1, acc1, 0, 0, 0);
        acc0 = MFMA16(zf[2], v2, acc0, 0, 0, 0);
        acc1 = MFMA16(zf[3], v3, acc1, 0, 0, 0);
    }

#pragma unroll 1   // keep the loop rolled (I$-resident hot body)
    for (int n = 0; n < 15; n++) {
        // ---- (1) issue ALL 13 block-(n+1) loads (volatile asm, no waits) ----
        const int rb = 16 * (n + 1) + col;
        floatx4 dnxt = gload16f(Dpair + (n + 1) * 256 + 4 * L);
        short8 vf0 = gload16(Wvb + rb * 128 + quad * 8);
        short8 vf1 = gload16(Wvb + rb * 128 + 32 + quad * 8);
        short8 vf2 = gload16(Wvb + rb * 128 + 64 + quad * 8);
        short8 vf3 = gload16(Wvb + rb * 128 + 96 + quad * 8);
        short8 hf0 = gload16(Drowsb + rb * 256 + 0 * 32 + quad * 8);
        short8 hf1 = gload16(Drowsb + rb * 256 + 1 * 32 + quad * 8);
        short8 hf2 = gload16(Drowsb + rb * 256 + 2 * 32 + quad * 8);
        short8 hf3 = gload16(Drowsb + rb * 256 + 3 * 32 + quad * 8);
        short8 hf4 = gload16(Drowsb + rb * 256 + 4 * 32 + quad * 8);
        short8 hf5 = gload16(Drowsb + rb * 256 + 5 * 32 + quad * 8);
        short8 hf6 = gload16(Drowsb + rb * 256 + 6 * 32 + quad * 8);
        short8 hf7 = gload16(Drowsb + rb * 256 + 7 * 32 + quad * 8);

        // ---- (2) stage current D tile; transpose acc+bias via LDS ----
        *(floatx4*)&dblk[4 * L] = dcur;
        const float bwv = bsh[16 * n + col];
#pragma unroll
        for (int r = 0; r < 4; r++)
            buf[quad * 4 + r][col] = acc0[r] + acc1[r] + bwv;

        float vl[16], wl[16];
#pragma unroll
        for (int p4 = 0; p4 < 4; p4++) {
            const float4 tv = *(const float4*)&buf[col][p4 * 4];  // LDS read
            vl[p4 * 4 + 0] = tv.x; vl[p4 * 4 + 1] = tv.y;
            vl[p4 * 4 + 2] = tv.z; vl[p4 * 4 + 3] = tv.w;
        }

        // ---- (3) triangle in pairs (pk-fma), D broadcast from LDS ----
        triangle16(vl, wl, dblk, &lamsh[16 * n]);

        // ---- (4) fold w block into its wsh chunk (half per parity) ----
        {
            float4 wa, wb;
            if (quad & 1) {
                wa = make_float4(wl[8], wl[9], wl[10], wl[11]);
                wb = make_float4(wl[12], wl[13], wl[14], wl[15]);
            } else {
                wa = make_float4(wl[0], wl[1], wl[2], wl[3]);
                wb = make_float4(wl[4], wl[5], wl[6], wl[7]);
            }
            const short8 nf = pack8v(wa, wb);
            if ((quad >> 1) == (n & 1)) wsh[(n >> 1) * 64 + L] = nf;
        }

        // ---- (4b) single drain; tie all load results so consumers can't
        //            be scheduled above the wait ----
        asm volatile("s_waitcnt vmcnt(0)"
            : "+v"(dnxt), "+v"(vf0), "+v"(vf1), "+v"(vf2), "+v"(vf3),
              "+v"(hf0), "+v"(hf1), "+v"(hf2), "+v"(hf3),
              "+v"(hf4), "+v"(hf5), "+v"(hf6), "+v"(hf7));

        // ---- (5) uniform MFMA phase for block n+1 (registers hot) ----
        floatx4 a0 = {0.f, 0.f, 0.f, 0.f}, a1 = {0.f, 0.f, 0.f, 0.f};
        a0 = MFMA16(zf[0], vf0, a0, 0, 0, 0);
        a1 = MFMA16(zf[1], vf1, a1, 0, 0, 0);
        a0 = MFMA16(zf[2], vf2, a0, 0, 0, 0);
        a1 = MFMA16(zf[3], vf3, a1, 0, 0, 0);
        a0 = MFMA16(wsh[0 * 64 + L], hf0, a0, 0, 0, 0);
        a1 = MFMA16(wsh[1 * 64 + L], hf1, a1, 0, 0, 0);
        a0 = MFMA16(wsh[2 * 64 + L], hf2, a0, 0, 0, 0);
        a1 = MFMA16(wsh[3 * 64 + L], hf3, a1, 0, 0, 0);
        a0 = MFMA16(wsh[4 * 64 + L], hf4, a0, 0, 0, 0);
        a1 = MFMA16(wsh[5 * 64 + L], hf5, a1, 0, 0, 0);
        a0 = MFMA16(wsh[6 * 64 + L], hf6, a0, 0, 0, 0);
        a1 = MFMA16(wsh[7 * 64 + L], hf7, a1, 0, 0, 0);
        acc0 = a0; acc1 = a1; dcur = dnxt;
    }

    // ---- peeled n = 15: triangle only (no next block) ----
    {
        *(floatx4*)&dblk[4 * L] = dcur;
        const float bwv = bsh[240 + col];
#pragma unroll
        for (int r = 0; r < 4; r++)
            buf[quad * 4 + r][col] = acc0[r] + acc1[r] + bwv;

        float vl[16], wl[16];
#pragma unroll
        for (int p4 = 0; p4 < 4; p4++) {
            const float4 tv = *(const float4*)&buf[col][p4 * 4];
            vl[p4 * 4 + 0] = tv.x; vl[p4 * 4 + 1] = tv.y;
            vl[p4 * 4 + 2] = tv.z; vl[p4 * 4 + 3] = tv.w;
        }

        triangle16(vl, wl, dblk, &lamsh[240]);

        float4 wa, wb;
        if (quad & 1) {
            wa = make_float4(wl[8], wl[9], wl[10], wl[11]);
            wb = make_float4(wl[12], wl[13], wl[14], wl[15]);
        } else {
            wa = make_float4(wl[0], wl[1], wl[2], wl[3]);
            wb = make_float4(wl[4], wl[5], wl[6], wl[7]);
        }
        const short8 nf = pack8v(wa, wb);
        if (quad >= 2) wsh[7 * 64 + L] = nf;      // n=15 odd -> quads 2,3
    }

    // ---- y phase: Y[16][32] = x@C2^T + W@D21^T + b_y ----
    floatx4 y0 = {0.f, 0.f, 0.f, 0.f}, y1 = {0.f, 0.f, 0.f, 0.f};
    {
        const short8 yc0 = *(const short8*)(C2b + col * 64 + quad * 8);
        const short8 yc1 = *(const short8*)(C2b + col * 64 + 32 + quad * 8);
        const short8 yc2 = *(const short8*)(C2b + (16 + col) * 64 + quad * 8);
        const short8 yc3 = *(const short8*)(C2b + (16 + col) * 64 + 32 + quad * 8);
        y0 = MFMA16(zf[0], yc0, y0, 0, 0, 0);
        y1 = MFMA16(zf[0], yc2, y1, 0, 0, 0);
        y0 = MFMA16(zf[1], yc1, y0, 0, 0, 0);
        y1 = MFMA16(zf[1], yc3, y1, 0, 0, 0);
    }
#pragma unroll
    for (int c = 0; c < 8; c++) {
        const short8 wfc = wsh[c * 64 + L];
        const short8 b0 = *(const short8*)(D21b + col * 256 + c * 32 + quad * 8);
        const short8 b1 = *(const short8*)(D21b + (16 + col) * 256 + c * 32 + quad * 8);
        y0 = MFMA16(wfc, b0, y0, 0, 0, 0);
        y1 = MFMA16(wfc, b1, y1, 0, 0, 0);
    }
    const float by0 = b[320 + col];
    const float by1 = b[336 + col];
#pragma unroll
    for (int r = 0; r < 4; r++) {
        out[(long)(row0 + quad * 4 + r) * 32 + col]      = y0[r] + by0;
        out[(long)(row0 + quad * 4 + r) * 32 + 16 + col] = y1[r] + by1;
    }
}

// ---------------------------------------------------------------------------
extern "C" void kernel_launch(void* const* d_in, const int* in_sizes, int n_in,
                              void* d_out, int out_size, void* d_ws, size_t ws_size,
                              hipStream_t stream)
{
    const float* u    = (const float*)d_in[0];
    const float* x0   = (const float*)d_in[1];
    const float* B2   = (const float*)d_in[2];
    const float* C2   = (const float*)d_in[3];
    const float* D12  = (const float*)d_in[4];
    const float* D21  = (const float*)d_in[5];
    const float* b    = (const float*)d_in[6];
    const float* X    = (const float*)d_in[7];
    // d_in[8] = Y1 (unused in forward)
    const float* St   = (const float*)d_in[9];
    const float* Q    = (const float*)d_in[10];
    const float* Rinv = (const float*)d_in[11];
    float* out = (float*)d_out;

    float* ws     = (float*)d_ws;
    float* lT1    = ws;                 // 384*64
    float* t1     = lT1 + 384 * 64;     // 384*64
    float* lT2    = t1 + 384 * 64;      // 384*32
    float* t2     = lT2 + 384 * 32;     // 384*32
    float* lamg   = t2 + 384 * 32;      // 256
    float* Dpair  = lamg + 256;         // 16*256 fp32 (pair-interleaved)
    unsigned short* Drowsb = (unsigned short*)(Dpair + 16 * 256); // 256*256
    unsigned short* Wvb    = Drowsb + 256 * 256;                  // 256*128
    unsigned short* C2b    = Wvb + 256 * 128;                     // 32*64
    unsigned short* D21b   = C2b + 32 * 64;                       // 32*256

    ren_prep13<<<dim3(800), dim3(64), 0, stream>>>(B2, C2, D12, D21, St, Q, Rinv,
                                                   lT1, t1, lT2, t2, Wvb, C2b, D21b);
    ren_prep2<<<dim3(256), dim3(320), 0, stream>>>(X, lT1, t1, lT2, t2,
                                                   Wvb, Drowsb, Dpair, lamg);

    const int batch = in_sizes[0] / 64;            // 32768
    ren_main<<<dim3(batch / 16), dim3(64), 0, stream>>>(u, x0, b, Wvb, Drowsb,
                                                        Dpair, lamg, C2b, D21b, out);
}

// Round 8
// 126.912 us; speedup vs baseline: 1.1833x; 1.1833x over previous
//
#include <hip/hip_runtime.h>
#include <hip/hip_bf16.h>

// REN forward: BATCH=32768, N_X=64, N_UNITS=256, N_Y=32, N_U=64
typedef __attribute__((ext_vector_type(8))) short short8;
typedef __attribute__((ext_vector_type(4))) float floatx4;
typedef __attribute__((ext_vector_type(2))) float floatx2;

#define MFMA16 __builtin_amdgcn_mfma_f32_16x16x32_bf16

__device__ inline unsigned short bf16_rn(float f) {
    return (unsigned short)((__float_as_uint(f) + 0x8000u) >> 16);
}
// Packed f32->bf16 (RNE), value-based: no address-taken private arrays.
__device__ __attribute__((always_inline)) inline short8 pack8v(float4 a, float4 b) {
    union { short8 s; unsigned int u[4]; } r;
    union { __hip_bfloat162 h; unsigned int u; } c;
    c.h = __float22bfloat162_rn(make_float2(a.x, a.y)); r.u[0] = c.u;
    c.h = __float22bfloat162_rn(make_float2(a.z, a.w)); r.u[1] = c.u;
    c.h = __float22bfloat162_rn(make_float2(b.x, b.y)); r.u[2] = c.u;
    c.h = __float22bfloat162_rn(make_float2(b.z, b.w)); r.u[3] = c.u;
    return r.s;
}

// ---------------------------------------------------------------------------
// Prep13: (unchanged)
// ---------------------------------------------------------------------------
__global__ __launch_bounds__(64) void ren_prep13(
    const float* __restrict__ B2, const float* __restrict__ C2,
    const float* __restrict__ D12, const float* __restrict__ D21,
    const float* __restrict__ St, const float* __restrict__ Q,
    const float* __restrict__ Rinv,
    float* __restrict__ lT1, float* __restrict__ t1,
    float* __restrict__ lT2, float* __restrict__ t2,
    unsigned short* __restrict__ Wvb, unsigned short* __restrict__ C2b,
    unsigned short* __restrict__ D21b)
{
    const int t = threadIdx.x;
    const int blk = blockIdx.x;
    if (blk >= 384) {   // bf16-copy role (uniform branch)
        const int id = (blk - 384) * 64 + t;
        if (id < 16384) {
            Wvb[(id >> 6) * 128 + 64 + (id & 63)] = bf16_rn(D12[id]);
        } else if (id < 16384 + 2048) {
            C2b[id - 16384] = bf16_rn(C2[id - 16384]);
        } else if (id < 16384 + 2048 + 8192) {
            D21b[id - 18432] = bf16_rn(D21[id - 18432]);
        }
        return;
    }

    __shared__ float stl[64 * 33];  // St (64x32), padded
    __shared__ float colbuf[32];    // this block's C2/D21 column
    __shared__ float s1[64];

    const int r = blk;   // 0..383
    const int c = t;     // 0..63
#pragma unroll
    for (int j = 0; j < 32; j++) {
        const int id = j * 64 + t;
        stl[(id >> 5) * 33 + (id & 31)] = St[id];
    }
    if (t < 32)
        colbuf[t] = (r < 64) ? C2[t * 64 + r]
                  : (r < 320 ? D21[t * 256 + (r - 64)] : 0.f);
    __syncthreads();

    float v1;
    if (r < 64) {
        float s = 0.f;
#pragma unroll
        for (int p = 0; p < 32; p++) s += stl[c * 33 + p] * colbuf[p];
        v1 = s;
    } else if (r < 320) {
        float s = 0.f;
#pragma unroll
        for (int p = 0; p < 32; p++) s += stl[c * 33 + p] * colbuf[p];
        v1 = s - D12[(r - 64) * 64 + c];
    } else {
        v1 = B2[(r - 320) * 64 + c];
    }
    s1[c] = v1;
    lT1[r * 64 + c] = v1;
    if (c < 32) {
        const float v2 = (r < 320) ? colbuf[c] : 0.f;
        lT2[r * 32 + c] = v2;
    }
    __syncthreads();

    float a = 0.f;
#pragma unroll
    for (int k = 0; k < 64; k++) a += s1[k] * Rinv[k * 64 + c];
    t1[r * 64 + c] = a;

    if (c < 32) {
        float bq = 0.f;
#pragma unroll
        for (int k = 0; k < 32; k++) bq += colbuf[k] * Q[k * 32 + c];
        t2[r * 32 + c] = bq;
    }
}

// ---------------------------------------------------------------------------
// Prep 2: (unchanged)
// ---------------------------------------------------------------------------
__global__ __launch_bounds__(320) void ren_prep2(
    const float* __restrict__ X,
    const float* __restrict__ lT1, const float* __restrict__ t1,
    const float* __restrict__ lT2, const float* __restrict__ t2,
    unsigned short* __restrict__ Wvb, unsigned short* __restrict__ Drowsb,
    float* __restrict__ Dpair, float* __restrict__ lamg)
{
    __shared__ float xcol[384];
    const int c = threadIdx.x;     // 0..319
    const int i = blockIdx.x;      // 0..255 -> H row 64+i
    for (int t = c; t < 384; t += 320) xcol[t] = X[t * 384 + 64 + i];
    __syncthreads();

    float f0 = 0.f, f1 = 0.f, f2 = 0.f, f3 = 0.f;
    float ac[8], au[8], bc8[8], bu[8];
#pragma unroll
    for (int kk = 0; kk < 8; kk++) { ac[kk] = X[kk * 384 + c]; au[kk] = xcol[kk]; }
    for (int k0 = 0; k0 < 384; k0 += 16) {
#pragma unroll
        for (int kk = 0; kk < 8; kk++) {
            bc8[kk] = X[(k0 + 8 + kk) * 384 + c]; bu[kk] = xcol[k0 + 8 + kk];
        }
        f0 += au[0] * ac[0]; f1 += au[1] * ac[1];
        f2 += au[2] * ac[2]; f3 += au[3] * ac[3];
        f0 += au[4] * ac[4]; f1 += au[5] * ac[5];
        f2 += au[6] * ac[6]; f3 += au[7] * ac[7];
        if (k0 + 16 < 384) {
#pragma unroll
            for (int kk = 0; kk < 8; kk++) {
                ac[kk] = X[(k0 + 16 + kk) * 384 + c]; au[kk] = xcol[k0 + 16 + kk];
            }
        }
        f0 += bu[0] * bc8[0]; f1 += bu[1] * bc8[1];
        f2 += bu[2] * bc8[2]; f3 += bu[3] * bc8[3];
        f0 += bu[4] * bc8[4]; f1 += bu[5] * bc8[5];
        f2 += bu[6] * bc8[6]; f3 += bu[7] * bc8[7];
    }

    const float* __restrict__ t1r = t1 + (64 + i) * 64;
    const float* __restrict__ l1r = lT1 + c * 64;
#pragma unroll
    for (int m4 = 0; m4 < 16; m4++) {
        const float4 lv = *(const float4*)(l1r + m4 * 4);
        f0 += t1r[m4 * 4 + 0] * lv.x; f1 += t1r[m4 * 4 + 1] * lv.y;
        f2 += t1r[m4 * 4 + 2] * lv.z; f3 += t1r[m4 * 4 + 3] * lv.w;
    }
    const float* __restrict__ t2r = t2 + (64 + i) * 32;
    const float* __restrict__ l2r = lT2 + c * 32;
#pragma unroll
    for (int m4 = 0; m4 < 8; m4++) {
        const float4 lv = *(const float4*)(l2r + m4 * 4);
        f0 -= t2r[m4 * 4 + 0] * lv.x; f1 -= t2r[m4 * 4 + 1] * lv.y;
        f2 -= t2r[m4 * 4 + 2] * lv.z; f3 -= t2r[m4 * 4 + 3] * lv.w;
    }
    float acc = (f0 + f1) + (f2 + f3) + (((64 + i) == c) ? 0.001f : 0.f);

    if (c < 64) {
        Wvb[i * 128 + c] = bf16_rn(-acc);       // C_1 = -H_21
    } else {
        const int cb = c - 64;
        if (cb == i) lamg[i] = 5.7707801635558536f / acc;  // (2*log2e)*2/H22ii
        if (i < 255) {
            const float dv = (cb <= i - 1) ? -acc : 0.f;
            Drowsb[(i + 1) * 256 + cb] = bf16_rn(dv);
            const int row = i + 1;
            if ((row >> 4) == (cb >> 4)) {      // diagonal 16-block, pair layout
                const int q = row & 15, p = cb & 15;
                Dpair[(row >> 4) * 256 + (q >> 1) * 32 + p * 2 + (q & 1)] = dv;
            }
        } else {
            Drowsb[cb] = 0;
        }
    }
}

// ---------------------------------------------------------------------------
// Fused two-tile triangle: both tiles' 16-unit tanh recursions in ONE tq
// loop. The dblk/lam LDS reads are shared (loaded once, used by both); the
// A/B FMA + exp chains are independent -> source-guaranteed interleave, so
// each tile's latency hides under the other's work. Constant-index private
// arrays only (SROA-safe).
// ---------------------------------------------------------------------------
__device__ __attribute__((always_inline)) inline void triangle16x2(
    float (&vlA)[16], float (&wlA)[16],
    float (&vlB)[16], float (&wlB)[16],
    const float* __restrict__ dblk, const float* __restrict__ lam)
{
#pragma unroll
    for (int tq = 0; tq < 8; tq++) {
        floatx2 aA, bA, aB, bB;
        aA[0] = vlA[2 * tq]; aA[1] = vlA[2 * tq + 1];
        aB[0] = vlB[2 * tq]; aB[1] = vlB[2 * tq + 1];
        bA[0] = 0.f; bA[1] = 0.f;
        bB[0] = 0.f; bB[1] = 0.f;
#pragma unroll
        for (int p4 = 0; p4 < tq; p4++) {
            const float4 d4 = *(const float4*)&dblk[tq * 32 + p4 * 4];  // LDS, shared
            floatx2 de; de[0] = d4.x; de[1] = d4.y;
            floatx2 dz; dz[0] = d4.z; dz[1] = d4.w;
            aA += de * wlA[2 * p4];  bA += dz * wlA[2 * p4 + 1];
            aB += de * wlB[2 * p4];  bB += dz * wlB[2 * p4 + 1];
        }
        aA += bA; aB += bB;
        floatx2 lm2; lm2[0] = lam[2 * tq]; lm2[1] = lam[2 * tq + 1];  // LDS, shared
        aA *= lm2; aB *= lm2;
        const float e0A = __builtin_amdgcn_exp2f(aA[0]);
        const float e1A = __builtin_amdgcn_exp2f(aA[1]);
        const float e0B = __builtin_amdgcn_exp2f(aB[0]);
        const float e1B = __builtin_amdgcn_exp2f(aB[1]);
        wlA[2 * tq]     = 1.f - 2.f * __builtin_amdgcn_rcpf(e0A + 1.f);
        wlA[2 * tq + 1] = 1.f - 2.f * __builtin_amdgcn_rcpf(e1A + 1.f);
        wlB[2 * tq]     = 1.f - 2.f * __builtin_amdgcn_rcpf(e0B + 1.f);
        wlB[2 * tq + 1] = 1.f - 2.f * __builtin_amdgcn_rcpf(e1B + 1.f);
    }
}

// ---------------------------------------------------------------------------
// Main — R15: TWO independent 16-row tiles per wave (32 batch rows/block,
// 1024 blocks). R10-R14 established that the per-wave dependency chain can't
// be shortened from source (load pinning defeated by regalloc 3 ways; DMA
// path failed correctness). So: overlap two chains instead. Operand loads
// (vf/hf/dnxt), dblk, lamsh, and all MFMA B-operands are SHARED between the
// tiles (issued once, consumed twice -> per-row load traffic halved); the
// latency-bound parts (transpose, triangle, MFMA accumulate) are duplicated
// and interleaved. Structure is exactly the clean-passing R10/R11 (plain
// loads, no asm, no DMA, wsh in LDS, rolled I$-resident loop).
// ---------------------------------------------------------------------------
__global__ __launch_bounds__(64, 1) void ren_main(
    const float* __restrict__ u, const float* __restrict__ x0,
    const float* __restrict__ b,
    const unsigned short* __restrict__ Wvb,
    const unsigned short* __restrict__ Drowsb,
    const float* __restrict__ Dpair,
    const float* __restrict__ lamg,
    const unsigned short* __restrict__ C2b,
    const unsigned short* __restrict__ D21b,
    float* __restrict__ out)
{
    __shared__ float bufA[16][20];  // tile A acc transpose (stride 20)
    __shared__ float bufB[16][20];  // tile B acc transpose
    __shared__ float dblk[256];     // pair-interleaved 16x16 D tile (shared)
    __shared__ float lamsh[256];
    __shared__ float bsh[256];
    __shared__ short8 wshA[8 * 64]; // tile A w A-frags
    __shared__ short8 wshB[8 * 64]; // tile B w A-frags

    const int L = threadIdx.x;
    const int col = L & 15;
    const int quad = L >> 4;
    const int row0 = blockIdx.x * 32;

#pragma unroll
    for (int j = 0; j < 4; j++) {
        lamsh[j * 64 + L] = lamg[j * 64 + L];
        bsh[j * 64 + L]   = b[64 + j * 64 + L];
    }
    const short8 zero8 = {0, 0, 0, 0, 0, 0, 0, 0};
#pragma unroll
    for (int c = 0; c < 8; c++) { wshA[c * 64 + L] = zero8; wshB[c * 64 + L] = zero8; }

    // z A-frags for both tiles: 4 K-chunks of 32 over [x0 | u]
    short8 zfA[4], zfB[4];
#pragma unroll
    for (int c = 0; c < 4; c++) {
        const float* base = (c < 2 ? x0 : u);
        const float* pA = base + (long)(row0 + col) * 64 + (c & 1) * 32 + quad * 8;
        const float* pB = base + (long)(row0 + 16 + col) * 64 + (c & 1) * 32 + quad * 8;
        zfA[c] = pack8v(*(const float4*)pA, *(const float4*)(pA + 4));
        zfB[c] = pack8v(*(const float4*)pB, *(const float4*)(pB + 4));
    }

    // ---- prologue: acc for block 0 (v-GEMM only), shared operands ----
    float4 dcur = *(const float4*)(Dpair + 4 * L);
    floatx4 accA0 = {0.f, 0.f, 0.f, 0.f}, accA1 = {0.f, 0.f, 0.f, 0.f};
    floatx4 accB0 = {0.f, 0.f, 0.f, 0.f}, accB1 = {0.f, 0.f, 0.f, 0.f};
    {
        short8 v0 = *(const short8*)(Wvb + col * 128 + quad * 8);
        short8 v1 = *(const short8*)(Wvb + col * 128 + 32 + quad * 8);
        short8 v2 = *(const short8*)(Wvb + col * 128 + 64 + quad * 8);
        short8 v3 = *(const short8*)(Wvb + col * 128 + 96 + quad * 8);
        accA0 = MFMA16(zfA[0], v0, accA0, 0, 0, 0);
        accB0 = MFMA16(zfB[0], v0, accB0, 0, 0, 0);
        accA1 = MFMA16(zfA[1], v1, accA1, 0, 0, 0);
        accB1 = MFMA16(zfB[1], v1, accB1, 0, 0, 0);
        accA0 = MFMA16(zfA[2], v2, accA0, 0, 0, 0);
        accB0 = MFMA16(zfB[2], v2, accB0, 0, 0, 0);
        accA1 = MFMA16(zfA[3], v3, accA1, 0, 0, 0);
        accB1 = MFMA16(zfB[3], v3, accB1, 0, 0, 0);
    }

#pragma unroll 1   // keep the loop rolled (I$-resident hot body)
    for (int n = 0; n < 15; n++) {
        // ---- (1) prefetch block-(n+1) operands (SHARED by both tiles) ----
        const int rb = 16 * (n + 1) + col;
        float4 dnxt = *(const float4*)(Dpair + (n + 1) * 256 + 4 * L);
        short8 vf[4];
#pragma unroll
        for (int c = 0; c < 4; c++)
            vf[c] = *(const short8*)(Wvb + rb * 128 + c * 32 + quad * 8);
        short8 hf[8];
#pragma unroll
        for (int c = 0; c < 8; c++)
            hf[c] = *(const short8*)(Drowsb + rb * 256 + c * 32 + quad * 8);

        // ---- (2) stage current D tile; transpose both tiles via LDS ----
        *(float4*)&dblk[4 * L] = dcur;
        const float bwv = bsh[16 * n + col];
#pragma unroll
        for (int r = 0; r < 4; r++) {
            bufA[quad * 4 + r][col] = accA0[r] + accA1[r] + bwv;
            bufB[quad * 4 + r][col] = accB0[r] + accB1[r] + bwv;
        }

        float vlA[16], wlA[16], vlB[16], wlB[16];
#pragma unroll
        for (int p4 = 0; p4 < 4; p4++) {
            const float4 ta = *(const float4*)&bufA[col][p4 * 4];  // LDS read
            const float4 tb = *(const float4*)&bufB[col][p4 * 4];
            vlA[p4 * 4 + 0] = ta.x; vlA[p4 * 4 + 1] = ta.y;
            vlA[p4 * 4 + 2] = ta.z; vlA[p4 * 4 + 3] = ta.w;
            vlB[p4 * 4 + 0] = tb.x; vlB[p4 * 4 + 1] = tb.y;
            vlB[p4 * 4 + 2] = tb.z; vlB[p4 * 4 + 3] = tb.w;
        }

        // ---- (3) fused two-tile triangle (chains interleaved) ----
        triangle16x2(vlA, wlA, vlB, wlB, dblk, &lamsh[16 * n]);

        // ---- (4) fold w blocks into wsh chunks (half per parity) ----
        {
            float4 waA, wbA, waB, wbB;
            if (quad & 1) {
                waA = make_float4(wlA[8], wlA[9], wlA[10], wlA[11]);
                wbA = make_float4(wlA[12], wlA[13], wlA[14], wlA[15]);
                waB = make_float4(wlB[8], wlB[9], wlB[10], wlB[11]);
                wbB = make_float4(wlB[12], wlB[13], wlB[14], wlB[15]);
            } else {
                waA = make_float4(wlA[0], wlA[1], wlA[2], wlA[3]);
                wbA = make_float4(wlA[4], wlA[5], wlA[6], wlA[7]);
                waB = make_float4(wlB[0], wlB[1], wlB[2], wlB[3]);
                wbB = make_float4(wlB[4], wlB[5], wlB[6], wlB[7]);
            }
            const short8 nfA = pack8v(waA, wbA);
            const short8 nfB = pack8v(waB, wbB);
            if ((quad >> 1) == (n & 1)) {
                wshA[(n >> 1) * 64 + L] = nfA;
                wshB[(n >> 1) * 64 + L] = nfB;
            }
        }

        // ---- (5) uniform MFMA phase for block n+1, both tiles ----
        floatx4 aA0 = {0.f, 0.f, 0.f, 0.f}, aA1 = {0.f, 0.f, 0.f, 0.f};
        floatx4 aB0 = {0.f, 0.f, 0.f, 0.f}, aB1 = {0.f, 0.f, 0.f, 0.f};
        aA0 = MFMA16(zfA[0], vf[0], aA0, 0, 0, 0);
        aB0 = MFMA16(zfB[0], vf[0], aB0, 0, 0, 0);
        aA1 = MFMA16(zfA[1], vf[1], aA1, 0, 0, 0);
        aB1 = MFMA16(zfB[1], vf[1], aB1, 0, 0, 0);
        aA0 = MFMA16(zfA[2], vf[2], aA0, 0, 0, 0);
        aB0 = MFMA16(zfB[2], vf[2], aB0, 0, 0, 0);
        aA1 = MFMA16(zfA[3], vf[3], aA1, 0, 0, 0);
        aB1 = MFMA16(zfB[3], vf[3], aB1, 0, 0, 0);
#pragma unroll
        for (int c = 0; c < 8; c++) {
            const short8 wA = wshA[c * 64 + L];   // zeros beyond current chunk
            const short8 wB = wshB[c * 64 + L];
            if (c & 1) {
                aA1 = MFMA16(wA, hf[c], aA1, 0, 0, 0);
                aB1 = MFMA16(wB, hf[c], aB1, 0, 0, 0);
            } else {
                aA0 = MFMA16(wA, hf[c], aA0, 0, 0, 0);
                aB0 = MFMA16(wB, hf[c], aB0, 0, 0, 0);
            }
        }
        accA0 = aA0; accA1 = aA1; accB0 = aB0; accB1 = aB1;
        dcur = dnxt;
    }

    // ---- peeled n = 15: triangles only (no next block) ----
    {
        *(float4*)&dblk[4 * L] = dcur;
        const float bwv = bsh[240 + col];
#pragma unroll
        for (int r = 0; r < 4; r++) {
            bufA[quad * 4 + r][col] = accA0[r] + accA1[r] + bwv;
            bufB[quad * 4 + r][col] = accB0[r] + accB1[r] + bwv;
        }

        float vlA[16], wlA[16], vlB[16], wlB[16];
#pragma unroll
        for (int p4 = 0; p4 < 4; p4++) {
            const float4 ta = *(const float4*)&bufA[col][p4 * 4];
            const float4 tb = *(const float4*)&bufB[col][p4 * 4];
            vlA[p4 * 4 + 0] = ta.x; vlA[p4 * 4 + 1] = ta.y;
            vlA[p4 * 4 + 2] = ta.z; vlA[p4 * 4 + 3] = ta.w;
            vlB[p4 * 4 + 0] = tb.x; vlB[p4 * 4 + 1] = tb.y;
            vlB[p4 * 4 + 2] = tb.z; vlB[p4 * 4 + 3] = tb.w;
        }

        triangle16x2(vlA, wlA, vlB, wlB, dblk, &lamsh[240]);

        float4 waA, wbA, waB, wbB;
        if (quad & 1) {
            waA = make_float4(wlA[8], wlA[9], wlA[10], wlA[11]);
            wbA = make_float4(wlA[12], wlA[13], wlA[14], wlA[15]);
            waB = make_float4(wlB[8], wlB[9], wlB[10], wlB[11]);
            wbB = make_float4(wlB[12], wlB[13], wlB[14], wlB[15]);
        } else {
            waA = make_float4(wlA[0], wlA[1], wlA[2], wlA[3]);
            wbA = make_float4(wlA[4], wlA[5], wlA[6], wlA[7]);
            waB = make_float4(wlB[0], wlB[1], wlB[2], wlB[3]);
            wbB = make_float4(wlB[4], wlB[5], wlB[6], wlB[7]);
        }
        const short8 nfA = pack8v(waA, wbA);
        const short8 nfB = pack8v(waB, wbB);
        if (quad >= 2) {                  // n=15 odd -> quads 2,3
            wshA[7 * 64 + L] = nfA;
            wshB[7 * 64 + L] = nfB;
        }
    }

    // ---- y phase: Y[16][32] per tile, shared B-operands ----
    floatx4 yA0 = {0.f, 0.f, 0.f, 0.f}, yA1 = {0.f, 0.f, 0.f, 0.f};
    floatx4 yB0 = {0.f, 0.f, 0.f, 0.f}, yB1 = {0.f, 0.f, 0.f, 0.f};
    {
        const short8 yc0 = *(const short8*)(C2b + col * 64 + quad * 8);
        const short8 yc1 = *(const short8*)(C2b + col * 64 + 32 + quad * 8);
        const short8 yc2 = *(const short8*)(C2b + (16 + col) * 64 + quad * 8);
        const short8 yc3 = *(const short8*)(C2b + (16 + col) * 64 + 32 + quad * 8);
        yA0 = MFMA16(zfA[0], yc0, yA0, 0, 0, 0);
        yB0 = MFMA16(zfB[0], yc0, yB0, 0, 0, 0);
        yA1 = MFMA16(zfA[0], yc2, yA1, 0, 0, 0);
        yB1 = MFMA16(zfB[0], yc2, yB1, 0, 0, 0);
        yA0 = MFMA16(zfA[1], yc1, yA0, 0, 0, 0);
        yB0 = MFMA16(zfB[1], yc1, yB0, 0, 0, 0);
        yA1 = MFMA16(zfA[1], yc3, yA1, 0, 0, 0);
        yB1 = MFMA16(zfB[1], yc3, yB1, 0, 0, 0);
    }
#pragma unroll
    for (int c = 0; c < 8; c++) {
        const short8 wA = wshA[c * 64 + L];
        const short8 wB = wshB[c * 64 + L];
        const short8 b0 = *(const short8*)(D21b + col * 256 + c * 32 + quad * 8);
        const short8 b1 = *(const short8*)(D21b + (16 + col) * 256 + c * 32 + quad * 8);
        yA0 = MFMA16(wA, b0, yA0, 0, 0, 0);
        yB0 = MFMA16(wB, b0, yB0, 0, 0, 0);
        yA1 = MFMA16(wA, b1, yA1, 0, 0, 0);
        yB1 = MFMA16(wB, b1, yB1, 0, 0, 0);
    }
    const float by0 = b[320 + col];
    const float by1 = b[336 + col];
#pragma unroll
    for (int r = 0; r < 4; r++) {
        out[(long)(row0 + quad * 4 + r) * 32 + col]           = yA0[r] + by0;
        out[(long)(row0 + quad * 4 + r) * 32 + 16 + col]      = yA1[r] + by1;
        out[(long)(row0 + 16 + quad * 4 + r) * 32 + col]      = yB0[r] + by0;
        out[(long)(row0 + 16 + quad * 4 + r) * 32 + 16 + col] = yB1[r] + by1;
    }
}

// ---------------------------------------------------------------------------
extern "C" void kernel_launch(void* const* d_in, const int* in_sizes, int n_in,
                              void* d_out, int out_size, void* d_ws, size_t ws_size,
                              hipStream_t stream)
{
    const float* u    = (const float*)d_in[0];
    const float* x0   = (const float*)d_in[1];
    const float* B2   = (const float*)d_in[2];
    const float* C2   = (const float*)d_in[3];
    const float* D12  = (const float*)d_in[4];
    const float* D21  = (const float*)d_in[5];
    const float* b    = (const float*)d_in[6];
    const float* X    = (const float*)d_in[7];
    // d_in[8] = Y1 (unused in forward)
    const float* St   = (const float*)d_in[9];
    const float* Q    = (const float*)d_in[10];
    const float* Rinv = (const float*)d_in[11];
    float* out = (float*)d_out;

    float* ws     = (float*)d_ws;
    float* lT1    = ws;                 // 384*64
    float* t1     = lT1 + 384 * 64;     // 384*64
    float* lT2    = t1 + 384 * 64;      // 384*32
    float* t2     = lT2 + 384 * 32;     // 384*32
    float* lamg   = t2 + 384 * 32;      // 256
    float* Dpair  = lamg + 256;         // 16*256 fp32 (pair-interleaved)
    unsigned short* Drowsb = (unsigned short*)(Dpair + 16 * 256); // 256*256
    unsigned short* Wvb    = Drowsb + 256 * 256;                  // 256*128
    unsigned short* C2b    = Wvb + 256 * 128;                     // 32*64
    unsigned short* D21b   = C2b + 32 * 64;                       // 32*256

    ren_prep13<<<dim3(800), dim3(64), 0, stream>>>(B2, C2, D12, D21, St, Q, Rinv,
                                                   lT1, t1, lT2, t2, Wvb, C2b, D21b);
    ren_prep2<<<dim3(256), dim3(320), 0, stream>>>(X, lT1, t1, lT2, t2,
                                                   Wvb, Drowsb, Dpair, lamg);

    const int batch = in_sizes[0] / 64;            // 32768
    ren_main<<<dim3(batch / 32), dim3(64), 0, stream>>>(u, x0, b, Wvb, Drowsb,
                                                        Dpair, lamg, C2b, D21b, out);
}